// Round 6
// baseline (107.744 us; speedup 1.0000x reference)
//
#include <hip/hip_runtime.h>
#include <hip/hip_fp16.h>
#include <hip/hip_bf16.h>

#define NL 26
#define ND 128
#define NT 64
#define NB 8192

typedef __attribute__((ext_vector_type(8))) short bf16x8;
typedef __attribute__((ext_vector_type(4))) float f32x4;

__device__ __forceinline__ uint32_t pk_bf16(float lo, float hi) {
    uint32_t r;
    asm("v_cvt_pk_bf16_f32 %0, %1, %2" : "=v"(r) : "v"(lo), "v"(hi));
    return r;
}

// ---------------------------------------------------------------------------
// Fused + chunk-pipelined: each wave owns 2 items. Time axis split into 4
// chunks of 16 steps. Per chunk: MFMA emissions (from register-prefetched X)
// -> LDS, issue NEXT chunk's X loads (stay in flight), run 16 DP steps whose
// VALU/LDS work hides the HBM latency. HBM demand is spread uniformly ->
// streaming overlaps DP instead of serializing (round-5: 43us + 42us serial).
// ---------------------------------------------------------------------------
__global__ __launch_bounds__(256, 3) void crf_fused(
    const float* __restrict__ X, const int* __restrict__ Y,
    const float* __restrict__ P, float* __restrict__ partials)
{
    __shared__ float TrS[NL * NL];                  // 2704 B
    __shared__ __half emS[4][2 * NT][32];           // 32 KB, [wave][item-row][label]
    __shared__ alignas(16) float pbuf[4][2][32];    // 1 KB
    __shared__ float itot[8];

    const int tid = threadIdx.x;
    for (int k = tid; k < NL * NL; k += 256) TrS[k] = P[NL * ND + k];
    __syncthreads();

    const int warp = tid >> 6;
    const int lane = tid & 63;
    const int r16  = lane & 15;   // A-row in tile / D col (label)
    const int kq   = lane >> 4;   // k-quarter / D row-quarter

    // ---- W fragments: label n = r16 + 16*h, k = kb*32 + kq*8 + j ----
    bf16x8 Bf[2][4];
    #pragma unroll
    for (int h = 0; h < 2; ++h) {
        int n = r16 + 16 * h;
        #pragma unroll
        for (int kb = 0; kb < 4; ++kb) {
            float w[8];
            if (n < NL) {
                const float4* wp = reinterpret_cast<const float4*>(P + n * ND + kb * 32 + kq * 8);
                float4 w0 = wp[0], w1 = wp[1];
                w[0]=w0.x; w[1]=w0.y; w[2]=w0.z; w[3]=w0.w;
                w[4]=w1.x; w[5]=w1.y; w[6]=w1.z; w[7]=w1.w;
            } else {
                #pragma unroll
                for (int jj = 0; jj < 8; ++jj) w[jj] = 0.f;
            }
            union { uint32_t u[4]; bf16x8 v; } pk;
            pk.u[0] = pk_bf16(w[0], w[1]); pk.u[1] = pk_bf16(w[2], w[3]);
            pk.u[2] = pk_bf16(w[4], w[5]); pk.u[3] = pk_bf16(w[6], w[7]);
            Bf[h][kb] = pk.v;
        }
    }

    const int item0 = blockIdx.x * 8 + warp * 2;
    const float4* X4 = reinterpret_cast<const float4*>(X);
    const size_t rowbase = (size_t)item0 * NT;   // 128 consecutive rows

    // ---- DP lane mapping (half-wave per item) ----
    const int half = lane >> 5;
    const int j    = lane & 31;
    const bool act = (j < NL);

    float Ecol[28];
    #pragma unroll
    for (int i = 0; i < NL; ++i) Ecol[i] = act ? __expf(TrS[i * NL + j]) : 0.f;
    Ecol[26] = 0.f; Ecol[27] = 0.f;

    const __half* em = &emS[warp][half * NT][0];     // [64][32]
    const int* y = Y + (size_t)(item0 + half) * NT;
    float* myp = pbuf[warp][half];

    int yprev = 0;
    float p = 0.f, emsc = 0.f, trsc = 0.f, M = 0.f;

    // ---- prefetch chunk 0 (both items, 16 steps' rows each) ----
    float4 xa[2][4][2];   // [item][kb][pair] = 64 VGPRs
    #pragma unroll
    for (int h = 0; h < 2; ++h)
        #pragma unroll
        for (int kb = 0; kb < 4; ++kb) {
            size_t row = rowbase + h * 64 + r16;
            size_t base = row * 32 + kb * 8 + kq * 2;
            xa[h][kb][0] = X4[base];
            xa[h][kb][1] = X4[base + 1];
        }

    #pragma unroll 1
    for (int c = 0; c < 4; ++c) {
        // -- emissions for chunk c (both items) from prefetched regs --
        #pragma unroll
        for (int h = 0; h < 2; ++h) {
            f32x4 acc0 = {0.f,0.f,0.f,0.f}, acc1 = {0.f,0.f,0.f,0.f};
            #pragma unroll
            for (int kb = 0; kb < 4; ++kb) {
                union { uint32_t u[4]; bf16x8 v; } A;
                A.u[0] = pk_bf16(xa[h][kb][0].x, xa[h][kb][0].y);
                A.u[1] = pk_bf16(xa[h][kb][0].z, xa[h][kb][0].w);
                A.u[2] = pk_bf16(xa[h][kb][1].x, xa[h][kb][1].y);
                A.u[3] = pk_bf16(xa[h][kb][1].z, xa[h][kb][1].w);
                acc0 = __builtin_amdgcn_mfma_f32_16x16x32_bf16(A.v, Bf[0][kb], acc0, 0, 0, 0);
                acc1 = __builtin_amdgcn_mfma_f32_16x16x32_bf16(A.v, Bf[1][kb], acc1, 0, 0, 0);
            }
            // D layout: col = lane&15, row = kq*4 + q   [m89-verified]
            int lr = h * 64 + c * 16 + kq * 4;
            #pragma unroll
            for (int q = 0; q < 4; ++q) {
                emS[warp][lr + q][r16]      = __float2half(__expf(acc0[q]) * 0.0625f);
                emS[warp][lr + q][r16 + 16] = __float2half(__expf(acc1[q]) * 0.0625f);
            }
        }

        // -- issue next chunk's X loads; stay in flight under the DP below --
        if (c < 3) {
            #pragma unroll
            for (int h = 0; h < 2; ++h)
                #pragma unroll
                for (int kb = 0; kb < 4; ++kb) {
                    size_t row = rowbase + h * 64 + (c + 1) * 16 + r16;
                    size_t base = row * 32 + kb * 8 + kq * 2;
                    xa[h][kb][0] = X4[base];
                    xa[h][kb][1] = X4[base + 1];
                }
        }

        // -- DP steps of chunk c (reads em chunk c from LDS, same wave) --
        int t = c * 16;
        if (c == 0) {
            yprev = y[0];
            p = act ? __half2float(em[j]) : 0.f;     // pe_0
            emsc = __logf(__half2float(em[yprev]));
            t = 1;
        }
        const int tend = c * 16 + 16;
        for (; t < tend; ++t) {
            myp[j] = p;                              // zeros for j>=26
            const int yt = y[t];
            trsc += TrS[yprev * NL + yt];
            yprev = yt;

            const float4* pp4 = reinterpret_cast<const float4*>(myp);
            float a0 = 0.f, a1 = 0.f;
            #pragma unroll
            for (int ip = 0; ip < 7; ++ip) {
                float4 q4 = pp4[ip];                 // uniform -> LDS broadcast
                a0 = fmaf(q4.x, Ecol[4 * ip],     a0);
                a1 = fmaf(q4.y, Ecol[4 * ip + 1], a1);
                a0 = fmaf(q4.z, Ecol[4 * ip + 2], a0);
                a1 = fmaf(q4.w, Ecol[4 * ip + 3], a1);
            }
            float pe = act ? __half2float(em[t * 32 + j]) : 0.f;
            p = (a0 + a1) * pe;
            emsc += __logf(__half2float(em[t * 32 + yt]));

            if ((t & 3) == 0) {                      // renorm every 4 steps
                float m = p;
                #pragma unroll
                for (int k = 16; k >= 1; k >>= 1) m = fmaxf(m, __shfl_xor(m, k));
                M += __logf(m);
                p *= (1.0f / m);
            }
        }
    }

    float s = p;
    #pragma unroll
    for (int k = 16; k >= 1; k >>= 1) s += __shfl_xor(s, k);
    float logZ = M + __logf(s);
    float tot = emsc + trsc - logZ;                  // 1/16 scale cancels

    if (j == 0) itot[warp * 2 + half] = tot;
    __syncthreads();
    if (tid == 0) {
        float sm = 0.f;
        #pragma unroll
        for (int i = 0; i < 8; ++i) sm += itot[i];
        partials[blockIdx.x] = sm;
    }
}

__global__ void crf_reduce2(const float* __restrict__ partials,
                            float* __restrict__ out, int n) {
    __shared__ float red[256];
    float s = 0.f;
    for (int i = threadIdx.x; i < n; i += 256) s += partials[i];
    red[threadIdx.x] = s;
    __syncthreads();
    for (int k = 128; k >= 1; k >>= 1) {
        if ((int)threadIdx.x < k) red[threadIdx.x] += red[threadIdx.x + k];
        __syncthreads();
    }
    if (threadIdx.x == 0) out[0] = -red[0] / (float)NB;
}

extern "C" void kernel_launch(void* const* d_in, const int* in_sizes, int n_in,
                              void* d_out, int out_size, void* d_ws, size_t ws_size,
                              hipStream_t stream) {
    const float* X = (const float*)d_in[0];
    const int*   Y = (const int*)d_in[1];
    const float* P = (const float*)d_in[2];
    float* out = (float*)d_out;
    float* partials = (float*)d_ws;   // 1024 floats

    crf_fused<<<NB / 8, 256, 0, stream>>>(X, Y, P, partials);
    crf_reduce2<<<1, 256, 0, stream>>>(partials, out, NB / 8);
}

// Round 7
// 80.239 us; speedup vs baseline: 1.3428x; 1.3428x over previous
//
#include <hip/hip_runtime.h>
#include <hip/hip_fp16.h>
#include <hip/hip_bf16.h>

#define NL 26
#define ND 128
#define NT 64
#define NB 8192
#define EMP 34   // padded em row stride in halfs (68 B, bank-spreading)

typedef __attribute__((ext_vector_type(8))) short bf16x8;
typedef __attribute__((ext_vector_type(4))) float f32x4;

__device__ __forceinline__ uint32_t pk_bf16(float lo, float hi) {
    uint32_t r;
    asm("v_cvt_pk_bf16_f32 %0, %1, %2" : "=v"(r) : "v"(lo), "v"(hi));
    return r;
}

// ROCm 7.2 hip_fp16.h lacks __hmax2; v_pk_max_f16 is gfx950-valid
__device__ __forceinline__ __half2 pkmax(__half2 a, __half2 b) {
    union { __half2 h; uint32_t u; } ua, ub, ur;
    ua.h = a; ub.h = b;
    asm("v_pk_max_f16 %0, %1, %2" : "=v"(ur.u) : "v"(ua.u), "v"(ub.u));
    return ur.h;
}

// ---------------------------------------------------------------------------
// Fused: block = 128 thr (2 waves), each wave owns 2 items end-to-end.
//  Phase A: bf16-MFMA emissions -> exp(em)/16 fp16 into wave-private LDS.
//  Gold:    parallel-over-t gold-path score (hoisted out of serial DP).
//  Phase B: exp-space DP; p broadcast fp16 (4x ds_read_b128), matvec via
//           13 v_pk_fma_f16, renorm computed lane-locally (no cross-lane).
// ---------------------------------------------------------------------------
__global__ __launch_bounds__(128, 4) void crf_fused(
    const float* __restrict__ X, const int* __restrict__ Y,
    const float* __restrict__ P, float* __restrict__ partials)
{
    __shared__ float TrS[NL * NL];                         // 2704 B
    __shared__ __half emS[2][2][NT][EMP];                  // 17408 B
    __shared__ alignas(16) __half2 pbuf[2][2][16];         // 256 B

    const int tid = threadIdx.x;
    for (int k = tid; k < NL * NL; k += 128) TrS[k] = P[NL * ND + k];
    __syncthreads();

    const int warp = tid >> 6;
    const int lane = tid & 63;
    const int r16  = lane & 15;   // A-row in tile / D col (label)
    const int kq   = lane >> 4;   // k-quarter / D row-quarter

    // ---- W fragments: label n = r16 + 16*h, k = kb*32 + kq*8 + j ----
    bf16x8 Bf[2][4];
    #pragma unroll
    for (int h = 0; h < 2; ++h) {
        int n = r16 + 16 * h;
        #pragma unroll
        for (int kb = 0; kb < 4; ++kb) {
            float w[8];
            if (n < NL) {
                const float4* wp = reinterpret_cast<const float4*>(P + n * ND + kb * 32 + kq * 8);
                float4 w0 = wp[0], w1 = wp[1];
                w[0]=w0.x; w[1]=w0.y; w[2]=w0.z; w[3]=w0.w;
                w[4]=w1.x; w[5]=w1.y; w[6]=w1.z; w[7]=w1.w;
            } else {
                #pragma unroll
                for (int jj = 0; jj < 8; ++jj) w[jj] = 0.f;
            }
            union { uint32_t u[4]; bf16x8 v; } pk;
            pk.u[0] = pk_bf16(w[0], w[1]); pk.u[1] = pk_bf16(w[2], w[3]);
            pk.u[2] = pk_bf16(w[4], w[5]); pk.u[3] = pk_bf16(w[6], w[7]);
            Bf[h][kb] = pk.v;
        }
    }

    const int item0 = blockIdx.x * 4 + warp * 2;
    const float4* X4 = reinterpret_cast<const float4*>(X);
    const size_t rowbase = (size_t)item0 * NT;   // 128 consecutive rows

    // ---- phase A: 8 tiles of 16 rows -> emS (exp(em)/16 as fp16) ----
    for (int tt = 0; tt < 8; ++tt) {
        size_t row = rowbase + tt * 16 + r16;
        float4 xa[4][2];
        #pragma unroll
        for (int kb = 0; kb < 4; ++kb) {
            size_t base = row * 32 + kb * 8 + kq * 2;   // float4 index
            xa[kb][0] = X4[base];
            xa[kb][1] = X4[base + 1];
        }
        f32x4 acc0 = {0.f,0.f,0.f,0.f}, acc1 = {0.f,0.f,0.f,0.f};
        #pragma unroll
        for (int kb = 0; kb < 4; ++kb) {
            union { uint32_t u[4]; bf16x8 v; } A;
            A.u[0] = pk_bf16(xa[kb][0].x, xa[kb][0].y);
            A.u[1] = pk_bf16(xa[kb][0].z, xa[kb][0].w);
            A.u[2] = pk_bf16(xa[kb][1].x, xa[kb][1].y);
            A.u[3] = pk_bf16(xa[kb][1].z, xa[kb][1].w);
            acc0 = __builtin_amdgcn_mfma_f32_16x16x32_bf16(A.v, Bf[0][kb], acc0, 0, 0, 0);
            acc1 = __builtin_amdgcn_mfma_f32_16x16x32_bf16(A.v, Bf[1][kb], acc1, 0, 0, 0);
        }
        // D layout: col = lane&15, row = kq*4 + q   [m89-verified]
        #pragma unroll
        for (int q = 0; q < 4; ++q) {
            int r = tt * 16 + kq * 4 + q;               // 0..127 within pair
            __half* dst = &emS[warp][r >> 6][r & 63][0];
            dst[r16]      = __float2half(__expf(acc0[q]) * 0.0625f);
            dst[r16 + 16] = __float2half(__expf(acc1[q]) * 0.0625f);
        }
    }

    // ---- phase B setup: half-wave per item ----
    const int hf = lane >> 5;
    const int j  = lane & 31;
    const bool act = (j < NL);
    const int item = item0 + hf;

    // E column pairs: Ec2[ip] = (exp(Tr[2ip][j]), exp(Tr[2ip+1][j]))
    __half2 Ec2[13];
    #pragma unroll
    for (int ip = 0; ip < 13; ++ip) {
        float ea = act ? __expf(TrS[(2 * ip) * NL + j])     : 0.f;
        float eb = act ? __expf(TrS[(2 * ip + 1) * NL + j]) : 0.f;
        Ec2[ip] = __floats2half2_rn(ea, eb);
    }

    const __half (*em)[EMP] = emS[warp][hf];   // [64][34]
    const int* y = Y + (size_t)item * NT;

    // ---- gold-path score, parallel over t (lane j covers t = j, 32+j) ----
    float gold = 0.f;
    #pragma unroll
    for (int seg = 0; seg < 2; ++seg) {
        int t = seg * 32 + j;
        int yt = y[t];
        gold += __logf(__half2float(em[t][yt]));
        if (t < NT - 1) gold += TrS[yt * NL + y[t + 1]];
    }
    #pragma unroll
    for (int k = 16; k >= 1; k >>= 1) gold += __shfl_xor(gold, k, 32);

    // ---- DP: p stored fp16 in pbuf; every lane reads full vector ----
    __half* myp = (__half*)pbuf[warp][hf];
    myp[j] = act ? em[0][j] : __float2half(0.f);     // p_0 = pe_0
    const float4* pp4 = reinterpret_cast<const float4*>(pbuf[warp][hf]);

    float M = 0.f, pn = 0.f;
    for (int t = 1; t < NT; ++t) {
        union { float4 f[4]; __half2 h2[16]; } U;
        U.f[0] = pp4[0]; U.f[1] = pp4[1]; U.f[2] = pp4[2]; U.f[3] = pp4[3];

        // lane-local max over the 26 read values (no cross-lane)
        __half2 m2 = U.h2[0];
        #pragma unroll
        for (int ip = 1; ip < 13; ++ip) m2 = pkmax(m2, U.h2[ip]);
        float m = fmaxf(__low2float(m2), __high2float(m2));
        m = fmaxf(m, 1e-30f);

        // unscaled fp16 matvec: acc2 = sum_i (p[2i],p[2i+1]) * (E[2i][j],E[2i+1][j])
        __half2 acc2 = __float2half2_rn(0.f);
        #pragma unroll
        for (int ip = 0; ip < 13; ++ip) acc2 = __hfma2(U.h2[ip], Ec2[ip], acc2);

        float pe = act ? __half2float(em[t][j]) : 0.f;
        // fold 1/m (renorm) and 1/16 (fp16 range guard) into f32 epilogue
        pn = (__low2float(acc2) + __high2float(acc2)) * pe
             * (0.0625f * __builtin_amdgcn_rcpf(m));
        M += __logf(m) + 2.7725887222f;              // + log 16
        myp[j] = __float2half(pn);
    }

    // logZ = M + log(sum_j p_final[j])
    float s = pn;                                    // 0 for j>=26
    #pragma unroll
    for (int k = 16; k >= 1; k >>= 1) s += __shfl_xor(s, k, 32);
    float logZ = M + __logf(s);
    float tot = gold - logZ;                         // 1/16 pe-scale cancels
    tot += __shfl_xor(tot, 32);                      // combine the two halves
    if (lane == 0) partials[blockIdx.x * 2 + warp] = tot;
}

__global__ void crf_reduce2(const float* __restrict__ partials,
                            float* __restrict__ out, int n) {
    __shared__ float red[256];
    float s = 0.f;
    for (int i = threadIdx.x; i < n; i += 256) s += partials[i];
    red[threadIdx.x] = s;
    __syncthreads();
    for (int k = 128; k >= 1; k >>= 1) {
        if ((int)threadIdx.x < k) red[threadIdx.x] += red[threadIdx.x + k];
        __syncthreads();
    }
    if (threadIdx.x == 0) out[0] = -red[0] / (float)NB;
}

extern "C" void kernel_launch(void* const* d_in, const int* in_sizes, int n_in,
                              void* d_out, int out_size, void* d_ws, size_t ws_size,
                              hipStream_t stream) {
    const float* X = (const float*)d_in[0];
    const int*   Y = (const int*)d_in[1];
    const float* P = (const float*)d_in[2];
    float* out = (float*)d_out;
    float* partials = (float*)d_ws;   // 4096 floats

    crf_fused<<<NB / 4, 128, 0, stream>>>(X, Y, P, partials);
    crf_reduce2<<<1, 256, 0, stream>>>(partials, out, NB / 2);
}

// Round 8
// 70.858 us; speedup vs baseline: 1.5206x; 1.1324x over previous
//
#include <hip/hip_runtime.h>
#include <hip/hip_fp16.h>
#include <hip/hip_bf16.h>

#define NL 26
#define ND 128
#define NT 64
#define NB 8192
#define NIPB 16   // items per block
#define EMJ 32    // padded label dim
#define EMI 16    // item dim

typedef __attribute__((ext_vector_type(8))) short bf16x8;
typedef __attribute__((ext_vector_type(4))) float f32x4;

__device__ __forceinline__ uint32_t pk_bf16(float lo, float hi) {
    uint32_t r;
    asm("v_cvt_pk_bf16_f32 %0, %1, %2" : "=v"(r) : "v"(lo), "v"(hi));
    return r;
}

// ---------------------------------------------------------------------------
// Fused: block = 256 thr (4 waves) owns 16 items.
//  Phase A: wave w emits t-slab [16w,16w+16) for all 16 items (bf16 MFMA GEMM,
//           X rows coalesced), storing exp(em)/16 fp16 TRANSPOSED emT[t][j][it].
//  Phase B (wave 0 only): gold score parallel over (it, t-window), then the
//           forward DP as a per-step 16x26 x 26x26 MFMA: p' = (p E) .* pe.
//           Cross-step lane transpose via 1.3KB LDS scratch; a consistent
//           k-permutation on A and B frags makes the repack a pure pk_bf16.
// ---------------------------------------------------------------------------
__global__ __launch_bounds__(256, 2) void crf_fused(
    const float* __restrict__ X, const int* __restrict__ Y,
    const float* __restrict__ P, float* __restrict__ partials)
{
    __shared__ float TrS[NL * NL];                 // 2704 B
    __shared__ __half emT[NT][EMJ][EMI];           // 65536 B
    __shared__ alignas(16) uint32_t pScr[16][20];  // 1280 B (pad 20 -> 16B-aligned b128)
    __shared__ float goldS[NIPB];                  // 64 B

    const int tid = threadIdx.x;
    for (int k = tid; k < NL * NL; k += 256) TrS[k] = P[NL * ND + k];
    __syncthreads();

    const int warp = tid >> 6;
    const int lane = tid & 63;
    const int r16  = lane & 15;
    const int kq   = lane >> 4;

    // ---- W fragments: label n = r16 + 16*h, k = kb*32 + kq*8 + j ----
    bf16x8 Bf[2][4];
    #pragma unroll
    for (int h = 0; h < 2; ++h) {
        int n = r16 + 16 * h;
        #pragma unroll
        for (int kb = 0; kb < 4; ++kb) {
            float w[8];
            if (n < NL) {
                const float4* wp = reinterpret_cast<const float4*>(P + n * ND + kb * 32 + kq * 8);
                float4 w0 = wp[0], w1 = wp[1];
                w[0]=w0.x; w[1]=w0.y; w[2]=w0.z; w[3]=w0.w;
                w[4]=w1.x; w[5]=w1.y; w[6]=w1.z; w[7]=w1.w;
            } else {
                #pragma unroll
                for (int jj = 0; jj < 8; ++jj) w[jj] = 0.f;
            }
            union { uint32_t u[4]; bf16x8 v; } pk;
            pk.u[0] = pk_bf16(w[0], w[1]); pk.u[1] = pk_bf16(w[2], w[3]);
            pk.u[2] = pk_bf16(w[4], w[5]); pk.u[3] = pk_bf16(w[6], w[7]);
            Bf[h][kb] = pk.v;
        }
    }

    const int item0 = blockIdx.x * NIPB;
    const int tbase = warp * 16;
    const float4* X4 = reinterpret_cast<const float4*>(X);

    auto tile_load = [&](int it, float4 (*xa)[2]) {
        size_t row  = (size_t)(item0 + it) * NT + tbase + r16;
        size_t base = row * 32 + kq * 2;
        #pragma unroll
        for (int kb = 0; kb < 4; ++kb) {
            xa[kb][0] = X4[base + kb * 8];
            xa[kb][1] = X4[base + kb * 8 + 1];
        }
    };
    auto tile_comp = [&](int it, float4 (*xa)[2]) {
        f32x4 acc0 = {0.f,0.f,0.f,0.f}, acc1 = {0.f,0.f,0.f,0.f};
        #pragma unroll
        for (int kb = 0; kb < 4; ++kb) {
            union { uint32_t u[4]; bf16x8 v; } A;
            A.u[0] = pk_bf16(xa[kb][0].x, xa[kb][0].y);
            A.u[1] = pk_bf16(xa[kb][0].z, xa[kb][0].w);
            A.u[2] = pk_bf16(xa[kb][1].x, xa[kb][1].y);
            A.u[3] = pk_bf16(xa[kb][1].z, xa[kb][1].w);
            acc0 = __builtin_amdgcn_mfma_f32_16x16x32_bf16(A.v, Bf[0][kb], acc0, 0, 0, 0);
            acc1 = __builtin_amdgcn_mfma_f32_16x16x32_bf16(A.v, Bf[1][kb], acc1, 0, 0, 0);
        }
        // D layout: col = lane&15 = label, row = kq*4+q = t-offset  [m89]
        #pragma unroll
        for (int q = 0; q < 4; ++q) {
            int t = tbase + kq * 4 + q;
            emT[t][r16][it]      = __float2half(__expf(acc0[q]) * 0.0625f);
            emT[t][r16 + 16][it] = __float2half(__expf(acc1[q]) * 0.0625f);
        }
    };

    // ---- phase A: 16 tiles, software double-buffered ----
    float4 xaA[4][2], xaB[4][2];
    tile_load(0, xaA);
    #pragma unroll 1
    for (int ip = 0; ip < 8; ++ip) {
        int itA = ip * 2, itB = ip * 2 + 1;
        tile_load(itB, xaB);
        tile_comp(itA, xaA);
        if (itB < NIPB - 1) tile_load(itB + 1, xaA);
        tile_comp(itB, xaB);
    }

    __syncthreads();
    if (warp != 0) return;

    // ================= phase B (wave 0 only) =================

    // ---- gold score: lane (it=r16, t-window kq*16..) ----
    {
        const int* yrow = Y + (size_t)(item0 + r16) * NT + kq * 16;
        const int4* y4 = reinterpret_cast<const int4*>(yrow);
        int4 a0 = y4[0], a1 = y4[1], a2 = y4[2], a3 = y4[3];
        int ys[17] = {a0.x,a0.y,a0.z,a0.w, a1.x,a1.y,a1.z,a1.w,
                      a2.x,a2.y,a2.z,a2.w, a3.x,a3.y,a3.z,a3.w, 0};
        if (kq < 3) ys[16] = yrow[16];
        float g = 0.f;
        #pragma unroll
        for (int e = 0; e < 16; ++e) {
            int t = kq * 16 + e;
            g += __logf(__half2float(emT[t][ys[e]][r16]));
            if (t < NT - 1) g += TrS[ys[e] * NL + ys[e + 1]];
        }
        g += __shfl_xor(g, 16);
        g += __shfl_xor(g, 32);
        if (kq == 0) goldS[r16] = g;
    }

    // ---- E fragments (B-operand), k-permuted: k-slot 2s -> label s,
    //      k-slot 2s+1 -> label s+16 ----
    bf16x8 Ef[2];
    #pragma unroll
    for (int h = 0; h < 2; ++h) {
        int n = r16 + 16 * h;
        union { uint32_t u[4]; bf16x8 v; } c;
        #pragma unroll
        for (int w = 0; w < 4; ++w) {
            int s = kq * 4 + w;
            float lo = (n < NL) ? __expf(TrS[s * NL + n]) : 0.f;          // s<16<NL
            float hi = (n < NL && s + 16 < NL) ? __expf(TrS[(s + 16) * NL + n]) : 0.f;
            c.u[w] = pk_bf16(lo, hi);
        }
        Ef[h] = c.v;
    }

    // ---- init p_0 = pe_0 (A-frag, lane r16 = item, same k-permutation) ----
    bf16x8 pfrag;
    {
        union { uint32_t u[4]; bf16x8 v; } c;
        #pragma unroll
        for (int w = 0; w < 4; ++w) {
            int s = kq * 4 + w;
            float lo = __half2float(emT[0][s][r16]);
            float hi = (s + 16 < NL) ? __half2float(emT[0][s + 16][r16]) : 0.f;
            c.u[w] = pk_bf16(lo, hi);
        }
        pfrag = c.v;
    }

    // ---- DP: p' = (p E) .* pe, renorm every 4 steps ----
    float M[4] = {0.f, 0.f, 0.f, 0.f};
    float pn0[4], pn1[4];
    const f32x4 zacc = {0.f, 0.f, 0.f, 0.f};
    #pragma unroll 1
    for (int t = 1; t < NT; ++t) {
        f32x4 d0 = __builtin_amdgcn_mfma_f32_16x16x32_bf16(pfrag, Ef[0], zacc, 0, 0, 0);
        f32x4 d1 = __builtin_amdgcn_mfma_f32_16x16x32_bf16(pfrag, Ef[1], zacc, 0, 0, 0);
        // pe: items kq*4..+3 at labels r16 / r16+16 (b64 reads)
        const __half2* pe0p = reinterpret_cast<const __half2*>(&emT[t][r16][kq * 4]);
        const __half2* pe1p = reinterpret_cast<const __half2*>(&emT[t][r16 + 16][kq * 4]);
        __half2 pe0a = pe0p[0], pe0b = pe0p[1];
        __half2 pe1a = pe1p[0], pe1b = pe1p[1];
        pn0[0] = d0[0] * __low2float(pe0a);  pn0[1] = d0[1] * __high2float(pe0a);
        pn0[2] = d0[2] * __low2float(pe0b);  pn0[3] = d0[3] * __high2float(pe0b);
        pn1[0] = d1[0] * __low2float(pe1a);  pn1[1] = d1[1] * __high2float(pe1a);
        pn1[2] = d1[2] * __low2float(pe1b);  pn1[3] = d1[3] * __high2float(pe1b);

        if ((t & 3) == 0) {                    // renorm (max over labels per item)
            #pragma unroll
            for (int q = 0; q < 4; ++q) {
                float m = fmaxf(pn0[q], pn1[q]);
                m = fmaxf(m, __shfl_xor(m, 1));
                m = fmaxf(m, __shfl_xor(m, 2));
                m = fmaxf(m, __shfl_xor(m, 4));
                m = fmaxf(m, __shfl_xor(m, 8));
                float r = __builtin_amdgcn_rcpf(m);
                pn0[q] *= r; pn1[q] *= r;
                M[q] += __logf(m);
            }
        }
        // repack to next A-frag via LDS transpose (labels (r16, r16+16) pack)
        #pragma unroll
        for (int q = 0; q < 4; ++q)
            pScr[kq * 4 + q][r16] = pk_bf16(pn0[q], pn1[q]);
        uint4 pw = *reinterpret_cast<const uint4*>(&pScr[r16][kq * 4]);
        union { uint4 u; bf16x8 v; } pc; pc.u = pw;
        pfrag = pc.v;
    }

    // ---- logZ and block total ----
    float tot = 0.f;
    #pragma unroll
    for (int q = 0; q < 4; ++q) {
        float s = pn0[q] + pn1[q];
        s += __shfl_xor(s, 1);
        s += __shfl_xor(s, 2);
        s += __shfl_xor(s, 4);
        s += __shfl_xor(s, 8);
        float logZ = M[q] + __logf(s);
        tot += goldS[kq * 4 + q] - logZ;       // 1/16 scales cancel exactly
    }
    tot += __shfl_xor(tot, 16);                // sum the 4 item-quads
    tot += __shfl_xor(tot, 32);
    if (lane == 0) partials[blockIdx.x] = tot;
}

__global__ void crf_reduce2(const float* __restrict__ partials,
                            float* __restrict__ out, int n) {
    __shared__ float red[256];
    float s = 0.f;
    for (int i = threadIdx.x; i < n; i += 256) s += partials[i];
    red[threadIdx.x] = s;
    __syncthreads();
    for (int k = 128; k >= 1; k >>= 1) {
        if ((int)threadIdx.x < k) red[threadIdx.x] += red[threadIdx.x + k];
        __syncthreads();
    }
    if (threadIdx.x == 0) out[0] = -red[0] / (float)NB;
}

extern "C" void kernel_launch(void* const* d_in, const int* in_sizes, int n_in,
                              void* d_out, int out_size, void* d_ws, size_t ws_size,
                              hipStream_t stream) {
    const float* X = (const float*)d_in[0];
    const int*   Y = (const int*)d_in[1];
    const float* P = (const float*)d_in[2];
    float* out = (float*)d_out;
    float* partials = (float*)d_ws;   // 512 floats

    crf_fused<<<NB / NIPB, 256, 0, stream>>>(X, Y, P, partials);
    crf_reduce2<<<1, 256, 0, stream>>>(partials, out, NB / NIPB);
}